// Round 16
// baseline (597.085 us; speedup 1.0000x reference)
//
#include <hip/hip_runtime.h>

#define BB 32
#define TT 2048
#define DD 256
#define HH 256
#define AA 128
#define CC 4367
#define CLS_LD 4480   // 35*128, padded WclsT leading dim
#define NSTEPS 22
#define NCHUNK 32     // att t-chunks (64 t each)

typedef unsigned short ushortT;
typedef unsigned int uintT;
typedef unsigned long long u64T;
using frag8 = __attribute__((ext_vector_type(8))) short;
using f32x4 = __attribute__((ext_vector_type(4))) float;

__device__ __forceinline__ float tanh_fast(float u) {
  float e = __expf(2.0f * u);
  return 1.0f - 2.0f / (e + 1.0f);
}
__device__ __forceinline__ float sigmoid_fast(float u) {
  return 1.0f / (1.0f + __expf(-u));
}
__device__ __forceinline__ ushortT f2bf(float f) {
  unsigned int u = __float_as_uint(f);
  unsigned int r = (u + 0x7FFFu + ((u >> 16) & 1u)) >> 16;
  return (ushortT)r;
}
__device__ __forceinline__ float bf2f(ushortT v) {
  return __uint_as_float(((unsigned int)v) << 16);
}

// ---------- prep: WclsT fp32 [256][4480] and WxT_bf bf16 [128][256] ----------
__global__ __launch_bounds__(256) void trans_kernel(
    const float* __restrict__ Wx, const float* __restrict__ W_cls,
    float* __restrict__ WclsT, ushortT* __restrict__ WxT_bf) {
  int blk = blockIdx.x;
  __shared__ float tile[32][33];
  const int li = threadIdx.x >> 5, lj = threadIdx.x & 31;
  if (blk < 1096) {  // W_cls 4367x256 -> WclsT 256x4480
    int i0 = (blk >> 3) * 32, j0 = (blk & 7) * 32;
#pragma unroll
    for (int k = 0; k < 4; ++k) {
      int i = i0 + li + k * 8;
      if (i < CC) tile[li + k * 8][lj] = W_cls[(size_t)i * 256 + j0 + lj];
    }
    __syncthreads();
#pragma unroll
    for (int k = 0; k < 4; ++k) {
      int j = j0 + li + k * 8, i = i0 + lj;
      if (i < CC) WclsT[(size_t)j * CLS_LD + i] = tile[lj][li + k * 8];
    }
  } else {  // Wx 256x128 -> WxT_bf 128x256
    blk -= 1096;  // 0..31
    int i0 = (blk >> 2) * 32, j0 = (blk & 3) * 32;
#pragma unroll
    for (int k = 0; k < 4; ++k)
      tile[li + k * 8][lj] = Wx[(size_t)(i0 + li + k * 8) * 128 + j0 + lj];
    __syncthreads();
#pragma unroll
    for (int k = 0; k < 4; ++k) {
      int j = j0 + li + k * 8;
      WxT_bf[(size_t)j * 256 + i0 + lj] = f2bf(tile[lj][li + k * 8]);
    }
  }
}

// ---------- xW via MFMA bf16: block = 128 rows of [BT,256] x [256,128] ----------
// CHANGE vs r15: register double-buffer — next K-iter's x/W loads issue right
// after the first barrier (raw, no dependent VALU), so they fly during the
// MFMA block and only drain at the second barrier (r11 pattern). fp32->bf16
// conversion moved to the write phase. Kernel was latency-bound (2 blocks/CU,
// serialized load->barrier->MFMA): 45.6 us at only 2 TB/s.
__global__ __launch_bounds__(256) void xw_mfma(
    const float* __restrict__ x, const ushortT* __restrict__ WxT_bf,
    ushortT* __restrict__ x_bf, ushortT* __restrict__ xW_ta) {
  __shared__ ushortT lds[2 * 128 * 72];  // sX | sW staging; reused as sT[128][136]
#define SX(r, c) lds[(r) * 72 + (c)]
#define SW(r, c) lds[128 * 72 + (r) * 72 + (c)]
#define ST(m, a) lds[(m) * 136 + (a)]
  const int tid = threadIdx.x;
  const int lane = tid & 63, w = tid >> 6;
  const int l15 = lane & 15, quad = lane >> 4;
  const int r0 = blockIdx.x * 128;
  const int row = tid >> 1, half = tid & 1;

  f32x4 acc[2][8];
#pragma unroll
  for (int mt = 0; mt < 2; ++mt)
#pragma unroll
    for (int nt = 0; nt < 8; ++nt) acc[mt][nt] = (f32x4){0.f, 0.f, 0.f, 0.f};

  float4 xraw[8];
  uint4 wraw[4];
  {  // initial loads (kk0 = 0)
    const float4* xp = (const float4*)(x + (size_t)(r0 + row) * DD + half * 32);
    const uint4* wp = (const uint4*)(WxT_bf + (size_t)row * DD + half * 32);
#pragma unroll
    for (int i = 0; i < 8; ++i) xraw[i] = xp[i];
#pragma unroll
    for (int i = 0; i < 4; ++i) wraw[i] = wp[i];
  }
  for (int it = 0; it < 4; ++it) {
    const int kk0 = it * 64;
    // convert + write current regs to LDS (+ x_bf write-through)
    {
      uint4 pk[4];
#pragma unroll
      for (int i = 0; i < 4; ++i) {
        float4 f0 = xraw[2 * i], f1 = xraw[2 * i + 1];
        pk[i].x = (uintT)f2bf(f0.x) | ((uintT)f2bf(f0.y) << 16);
        pk[i].y = (uintT)f2bf(f0.z) | ((uintT)f2bf(f0.w) << 16);
        pk[i].z = (uintT)f2bf(f1.x) | ((uintT)f2bf(f1.y) << 16);
        pk[i].w = (uintT)f2bf(f1.z) | ((uintT)f2bf(f1.w) << 16);
      }
      uint4* sxp = (uint4*)&SX(row, half * 32);
      uint4* gxp = (uint4*)(x_bf + (size_t)(r0 + row) * DD + kk0 + half * 32);
      uint4* swp = (uint4*)&SW(row, half * 32);
#pragma unroll
      for (int i = 0; i < 4; ++i) { sxp[i] = pk[i]; gxp[i] = pk[i]; }
#pragma unroll
      for (int i = 0; i < 4; ++i) swp[i] = wraw[i];
    }
    __syncthreads();
    if (it < 3) {  // prefetch next K-iter: in flight during the MFMA block
      const int kn = kk0 + 64;
      const float4* xp = (const float4*)(x + (size_t)(r0 + row) * DD + kn + half * 32);
      const uint4* wp = (const uint4*)(WxT_bf + (size_t)row * DD + kn + half * 32);
#pragma unroll
      for (int i = 0; i < 8; ++i) xraw[i] = xp[i];
#pragma unroll
      for (int i = 0; i < 4; ++i) wraw[i] = wp[i];
    }
#pragma unroll
    for (int kk = 0; kk < 2; ++kk) {
      frag8 a0 = *(const frag8*)&SX(w * 32 + l15, kk * 32 + quad * 8);
      frag8 a1 = *(const frag8*)&SX(w * 32 + 16 + l15, kk * 32 + quad * 8);
#pragma unroll
      for (int nt = 0; nt < 8; ++nt) {
        frag8 bf = *(const frag8*)&SW(nt * 16 + l15, kk * 32 + quad * 8);
        acc[0][nt] = __builtin_amdgcn_mfma_f32_16x16x32_bf16(a0, bf, acc[0][nt], 0, 0, 0);
        acc[1][nt] = __builtin_amdgcn_mfma_f32_16x16x32_bf16(a1, bf, acc[1][nt], 0, 0, 0);
      }
    }
    __syncthreads();
  }
  // natural-order bounce: sT[m][a] = D[m][a], then write xW_ta[(r0+m)][a]
#pragma unroll
  for (int mt = 0; mt < 2; ++mt)
#pragma unroll
    for (int nt = 0; nt < 8; ++nt)
#pragma unroll
      for (int r = 0; r < 4; ++r) {
        int m = w * 32 + mt * 16 + quad * 4 + r;
        int a = nt * 16 + l15;
        ST(m, a) = f2bf(acc[mt][nt][r]);
      }
  __syncthreads();
  {
    const uint4* sp = (const uint4*)&ST(row, half * 64);
    uint4* gp = (uint4*)(xW_ta + (size_t)(r0 + row) * AA + half * 64);
#pragma unroll
    for (int i = 0; i < 8; ++i) gp[i] = sp[i];
  }
#undef SX
#undef SW
#undef ST
}

// ---------- gates v3: 2 b's per block — weight rows read once, used twice ----------
// grid (16 slices, 16 b-pairs), 256 thr. Halves the dominant gates traffic
// (W_ih/W_hh re-read: 50 -> 25 MB/step) and doubles FMA-per-load ILP.
// Structure otherwise r14-exact (in-register h-combine + partial hWh).
__global__ __launch_bounds__(256) void gates_kernel(
    const float* __restrict__ ctx_part, const float* __restrict__ den_part,
    const float* __restrict__ hall_c, const float* __restrict__ W_ih,
    const float* __restrict__ W_hh, const float* __restrict__ b_ih,
    const float* __restrict__ b_hh, const float* __restrict__ Wh,
    float* __restrict__ hall, float* __restrict__ hWh_part, int s) {
  const int sl = blockIdx.x, bp = blockIdx.y, tid = threadIdx.x;
  const int b0 = bp * 2;
  __shared__ __align__(16) float sctx[2][DD];
  __shared__ float sden[2];
  __shared__ float sh16[2][16];
  if (tid < 64) {  // den partial reduce: lanes 0-31 -> b0, 32-63 -> b0+1
    const int bb = tid >> 5, l = tid & 31;
    float d = den_part[(b0 + bb) * NCHUNK + l];
#pragma unroll
    for (int off = 16; off > 0; off >>= 1) d += __shfl_down(d, off, 32);
    if (l == 0) sden[bb] = d;
  }
#pragma unroll
  for (int bb = 0; bb < 2; ++bb) {  // ctx partial reduce, both b's, coalesced
    float acc = 0.f;
#pragma unroll
    for (int c = 0; c < NCHUNK; ++c)
      acc += ctx_part[((size_t)(b0 + bb) * NCHUNK + c) * DD + tid];
    sctx[bb][tid] = acc;
  }
  __syncthreads();
  const float invd0 = 1.0f / sden[0], invd1 = 1.0f / sden[1];
  const int kq = tid & 15, gsub = tid >> 4;  // gsub 0..15 = element within slice
  float4 c4[2][4], h4[2][4];
#pragma unroll
  for (int j = 0; j < 4; ++j) {
    float4 cv = ((const float4*)sctx[0])[kq * 4 + j];
    c4[0][j].x = cv.x * invd0; c4[0][j].y = cv.y * invd0;
    c4[0][j].z = cv.z * invd0; c4[0][j].w = cv.w * invd0;
    cv = ((const float4*)sctx[1])[kq * 4 + j];
    c4[1][j].x = cv.x * invd1; c4[1][j].y = cv.y * invd1;
    c4[1][j].z = cv.z * invd1; c4[1][j].w = cv.w * invd1;
    h4[0][j].x = 0.f; h4[0][j].y = 0.f; h4[0][j].z = 0.f; h4[0][j].w = 0.f;
    h4[1][j] = h4[0][j];
  }
  if (s >= 2) {
#pragma unroll
    for (int bb = 0; bb < 2; ++bb) {
      const float4* hp = (const float4*)(hall_c + ((size_t)(s - 2) * BB + b0 + bb) * HH) + kq * 4;
#pragma unroll
      for (int j = 0; j < 4; ++j) h4[bb][j] = hp[j];
    }
  }
  float gi_g[2][3], gh_g[2][3];
#pragma unroll
  for (int it = 0; it < 3; ++it) {
    const int g = it * 256 + sl * 16 + gsub;
    const float4* wi = (const float4*)(W_ih + (size_t)g * DD) + kq * 4;
    const float4* wh = (const float4*)(W_hh + (size_t)g * HH) + kq * 4;
    float gi0 = 0.f, gi1 = 0.f, gh0 = 0.f, gh1 = 0.f;
#pragma unroll
    for (int j = 0; j < 4; ++j) {
      float4 wv = wi[j];
      gi0 += c4[0][j].x * wv.x + c4[0][j].y * wv.y + c4[0][j].z * wv.z + c4[0][j].w * wv.w;
      gi1 += c4[1][j].x * wv.x + c4[1][j].y * wv.y + c4[1][j].z * wv.z + c4[1][j].w * wv.w;
      wv = wh[j];
      gh0 += h4[0][j].x * wv.x + h4[0][j].y * wv.y + h4[0][j].z * wv.z + h4[0][j].w * wv.w;
      gh1 += h4[1][j].x * wv.x + h4[1][j].y * wv.y + h4[1][j].z * wv.z + h4[1][j].w * wv.w;
    }
#pragma unroll
    for (int off = 8; off > 0; off >>= 1) {
      gi0 += __shfl_down(gi0, off, 16);
      gi1 += __shfl_down(gi1, off, 16);
      gh0 += __shfl_down(gh0, off, 16);
      gh1 += __shfl_down(gh1, off, 16);
    }
    gi_g[0][it] = gi0 + b_ih[g];  // valid on kq==0 (the only consumer)
    gi_g[1][it] = gi1 + b_ih[g];
    gh_g[0][it] = gh0 + b_hh[g];
    gh_g[1][it] = gh1 + b_hh[g];
  }
  if (kq == 0) {  // h-combine for element i = sl*16 + gsub, both b's, in registers
    const int i = sl * 16 + gsub;
#pragma unroll
    for (int bb = 0; bb < 2; ++bb) {
      float hp = (s >= 2) ? hall_c[((size_t)(s - 2) * BB + b0 + bb) * HH + i] : 0.f;
      float r = sigmoid_fast(gi_g[bb][0] + gh_g[bb][0]);
      float z = sigmoid_fast(gi_g[bb][1] + gh_g[bb][1]);
      float n = tanh_fast(gi_g[bb][2] + r * gh_g[bb][2]);
      float hv = (1.f - z) * n + z * hp;
      hall[((size_t)(s - 1) * BB + b0 + bb) * HH + i] = hv;
      sh16[bb][gsub] = hv;
    }
  }
  __syncthreads();
  {  // partial hWh over this block's 16 k's; thread = (bb = tid>>7, a = tid&127)
    const int bb = tid >> 7, a = tid & 127;
    float acc = 0.f;
#pragma unroll
    for (int k = 0; k < 16; ++k)
      acc = fmaf(sh16[bb][k], Wh[(size_t)(sl * 16 + k) * AA + a], acc);
    hWh_part[((size_t)(b0 + bb) * 16 + sl) * AA + a] = acc;
  }
}

// ---------- per-step attention (r15-exact). grid (32 b, 32 chunks), 256 thr ----------
__global__ __launch_bounds__(256, 4) void att_kernel(
    const ushortT* __restrict__ x_bf, const ushortT* __restrict__ xW_ta,
    const float* __restrict__ hWh_part, const float* __restrict__ v,
    float* __restrict__ ctx_part, float* __restrict__ den_part) {
  const int tid = threadIdx.x;
  const int b = blockIdx.x;
  const int chunk = blockIdx.y;  // 0..31, 64 t's each
  const int t0 = chunk * 64;
  __shared__ float sh_hWh[AA], sh_v[AA];
  __shared__ float sh_w[64];
  __shared__ __align__(16) float sh_ctx[4 * DD];
  if (tid < AA) {
    float hw = 0.f;
    if (hWh_part) {
#pragma unroll
      for (int sl = 0; sl < 16; ++sl)
        hw += hWh_part[((size_t)b * 16 + sl) * AA + tid];
    }
    sh_hWh[tid] = hw;
    sh_v[tid] = v[tid];
  }
  __syncthreads();  // waits only the 128-lane LDS stores above
  // x prefetch issues HERE: overlaps with all of Phase A (r11 win)
  const int j4 = tid >> 6, dq = tid & 63;
  u64T xr[16];
  {
    const u64T* xb4 = (const u64T*)x_bf;
#pragma unroll
    for (int j = 0; j < 16; ++j)
      xr[j] = xb4[(((size_t)(b * TT + t0 + j * 4 + j4)) * DD >> 2) + dq];
  }
  // Phase A: scores. thread = (tl = tid>>2 in [0,64), aseg = tid&3 owns 32 a's)
  {
    const int tl = tid >> 2, aseg = tid & 3;
    const uint4* xw16 = (const uint4*)(xW_ta + (size_t)(b * TT + t0 + tl) * AA + aseg * 32);
    float e = 0.f;
#pragma unroll
    for (int i = 0; i < 4; ++i) {
      uint4 u = xw16[i];
      const int ab = aseg * 32 + i * 8;
      e = fmaf(tanh_fast(bf2f((ushortT)(u.x & 0xFFFFu)) + sh_hWh[ab + 0]), sh_v[ab + 0], e);
      e = fmaf(tanh_fast(bf2f((ushortT)(u.x >> 16)) + sh_hWh[ab + 1]), sh_v[ab + 1], e);
      e = fmaf(tanh_fast(bf2f((ushortT)(u.y & 0xFFFFu)) + sh_hWh[ab + 2]), sh_v[ab + 2], e);
      e = fmaf(tanh_fast(bf2f((ushortT)(u.y >> 16)) + sh_hWh[ab + 3]), sh_v[ab + 3], e);
      e = fmaf(tanh_fast(bf2f((ushortT)(u.z & 0xFFFFu)) + sh_hWh[ab + 4]), sh_v[ab + 4], e);
      e = fmaf(tanh_fast(bf2f((ushortT)(u.z >> 16)) + sh_hWh[ab + 5]), sh_v[ab + 5], e);
      e = fmaf(tanh_fast(bf2f((ushortT)(u.w & 0xFFFFu)) + sh_hWh[ab + 6]), sh_v[ab + 6], e);
      e = fmaf(tanh_fast(bf2f((ushortT)(u.w >> 16)) + sh_hWh[ab + 7]), sh_v[ab + 7], e);
    }
    e += __shfl_xor(e, 1, 4);
    e += __shfl_xor(e, 2, 4);
    if (aseg == 0) sh_w[tl] = __expf(e);  // |e| <= ||v||_1 ~ 5: safe, no max-pass
  }
  __syncthreads();
  // Phase B: ctx partials from prefetched regs (unpack u64 -> 4 bf16)
  {
    float4 acc = {0.f, 0.f, 0.f, 0.f};
#pragma unroll
    for (int j = 0; j < 16; ++j) {
      float w = sh_w[j * 4 + j4];
      u64T u = xr[j];
      acc.x = fmaf(w, bf2f((ushortT)(u       & 0xFFFFu)), acc.x);
      acc.y = fmaf(w, bf2f((ushortT)((u >> 16) & 0xFFFFu)), acc.y);
      acc.z = fmaf(w, bf2f((ushortT)((u >> 32) & 0xFFFFu)), acc.z);
      acc.w = fmaf(w, bf2f((ushortT)((u >> 48) & 0xFFFFu)), acc.w);
    }
    ((float4*)sh_ctx)[j4 * 64 + dq] = acc;
  }
  __syncthreads();
  {
    float sum = sh_ctx[tid] + sh_ctx[DD + tid] + sh_ctx[2 * DD + tid] + sh_ctx[3 * DD + tid];
    ctx_part[((size_t)b * NCHUNK + chunk) * DD + tid] = sum;  // plain coalesced store
  }
  if (tid < 64) {
    float ds = sh_w[tid];
#pragma unroll
    for (int off = 32; off > 0; off >>= 1) ds += __shfl_down(ds, off, 64);
    if (tid == 0) den_part[b * NCHUNK + chunk] = ds;
  }
}

// ---------- final: out[b,s,c] = hall[s,b,:] @ W_cls^T + b_cls ----------
// r1-EXACT (measured 45.0 us — best of 5 variants; cls frozen).
__global__ __launch_bounds__(256) void cls_kernel(
    const float* __restrict__ hall, const float* __restrict__ WclsT,
    const float* __restrict__ b_cls, float* __restrict__ out) {
  const int tid = threadIdx.x;
  const int c0 = blockIdx.x * 128;
  const int r0 = blockIdx.y * 32;
  const int cq = tid & 31, rg = tid >> 5;
  const int c = c0 + cq * 4;
  __shared__ __align__(16) float shh[32 * HH];
  {
    const float4* hsrc = (const float4*)(hall + (size_t)r0 * HH);
    float4* hdst = (float4*)shh;
#pragma unroll
    for (int i = 0; i < 8; ++i) hdst[tid + 256 * i] = hsrc[tid + 256 * i];
  }
  __syncthreads();
  float acc[4][4];
#pragma unroll
  for (int j = 0; j < 4; ++j)
#pragma unroll
    for (int l = 0; l < 4; ++l) acc[j][l] = 0.f;
#pragma unroll 4
  for (int k = 0; k < HH; ++k) {
    float4 w4 = *(const float4*)(WclsT + (size_t)k * CLS_LD + c);
    float h0 = shh[(rg * 4 + 0) * HH + k];
    float h1 = shh[(rg * 4 + 1) * HH + k];
    float h2 = shh[(rg * 4 + 2) * HH + k];
    float h3 = shh[(rg * 4 + 3) * HH + k];
    acc[0][0] = fmaf(h0, w4.x, acc[0][0]); acc[0][1] = fmaf(h0, w4.y, acc[0][1]);
    acc[0][2] = fmaf(h0, w4.z, acc[0][2]); acc[0][3] = fmaf(h0, w4.w, acc[0][3]);
    acc[1][0] = fmaf(h1, w4.x, acc[1][0]); acc[1][1] = fmaf(h1, w4.y, acc[1][1]);
    acc[1][2] = fmaf(h1, w4.z, acc[1][2]); acc[1][3] = fmaf(h1, w4.w, acc[1][3]);
    acc[2][0] = fmaf(h2, w4.x, acc[2][0]); acc[2][1] = fmaf(h2, w4.y, acc[2][1]);
    acc[2][2] = fmaf(h2, w4.z, acc[2][2]); acc[2][3] = fmaf(h2, w4.w, acc[2][3]);
    acc[3][0] = fmaf(h3, w4.x, acc[3][0]); acc[3][1] = fmaf(h3, w4.y, acc[3][1]);
    acc[3][2] = fmaf(h3, w4.z, acc[3][2]); acc[3][3] = fmaf(h3, w4.w, acc[3][3]);
  }
#pragma unroll
  for (int j = 0; j < 4; ++j) {
    int row = r0 + rg * 4 + j;  // row = s*BB + b
    int bb = row & (BB - 1), st = row >> 5;
    size_t obase = ((size_t)bb * NSTEPS + st) * CC;
#pragma unroll
    for (int l = 0; l < 4; ++l) {
      int cc = c + l;
      if (cc < CC) out[obase + cc] = acc[j][l] + b_cls[cc];
    }
  }
}

extern "C" void kernel_launch(void* const* d_in, const int* in_sizes, int n_in,
                              void* d_out, int out_size, void* d_ws, size_t ws_size,
                              hipStream_t stream) {
  const float* x     = (const float*)d_in[0];
  const float* Wx    = (const float*)d_in[1];
  const float* Wh    = (const float*)d_in[2];
  const float* v     = (const float*)d_in[3];
  const float* W_ih  = (const float*)d_in[4];
  const float* W_hh  = (const float*)d_in[5];
  const float* b_ih  = (const float*)d_in[6];
  const float* b_hh  = (const float*)d_in[7];
  const float* W_cls = (const float*)d_in[8];
  const float* b_cls = (const float*)d_in[9];
  float* out = (float*)d_out;

  // workspace
  float* ctx_part = (float*)d_ws;                           // 32*32*256
  float* den_part = ctx_part + (size_t)BB * NCHUNK * DD;    // 32*32
  float* hWh_part = den_part + BB * NCHUNK;                 // 32*16*128
  float* hall     = hWh_part + (size_t)BB * 16 * AA;        // 22*32*256
  float* WclsT    = hall + (size_t)NSTEPS * BB * HH;        // 256*4480
  ushortT* WxT_bf = (ushortT*)(WclsT + (size_t)256 * CLS_LD);  // 128*256
  ushortT* x_bf   = WxT_bf + 128 * 256;                     // BT*256
  ushortT* xW_ta  = x_bf + (size_t)BB * TT * DD;            // B*T*A

  trans_kernel<<<1096 + 32, 256, 0, stream>>>(Wx, W_cls, WclsT, WxT_bf);
  xw_mfma<<<(BB * TT) / 128, 256, 0, stream>>>(x, WxT_bf, x_bf, xW_ta);

  att_kernel<<<dim3(BB, NCHUNK), 256, 0, stream>>>(x_bf, xW_ta, nullptr, v, ctx_part, den_part);
  for (int s = 1; s <= NSTEPS; ++s) {
    gates_kernel<<<dim3(16, 16), 256, 0, stream>>>(ctx_part, den_part, hall, W_ih, W_hh,
                                                   b_ih, b_hh, Wh, hall, hWh_part, s);
    if (s < NSTEPS)
      att_kernel<<<dim3(BB, NCHUNK), 256, 0, stream>>>(x_bf, xW_ta, hWh_part, v, ctx_part, den_part);
  }
  cls_kernel<<<dim3(35, 22), 256, 0, stream>>>(hall, WclsT, b_cls, out);
}